// Round 22
// baseline (54.545 us; speedup 1.0000x reference)
//
#include <hip/hip_runtime.h>
#include <hip/hip_bf16.h>

#define VIEWS 16
#define BSZ 512
#define NROWS 8192
#define D 128
#define CSPLIT 16          // B-panel split (grid dim)
#define CSPLIT_OUT 32      // epart slices = CSPLIT * 2 col-halves
#define BCOLS 64
#define NSVC 100

typedef short bf16x8 __attribute__((ext_vector_type(8)));
typedef float f32x4 __attribute__((ext_vector_type(4)));

// log2(e)/0.07
constexpr float C1 = 20.609929155556618f;
constexpr float INV_T = 14.285714285714286f;

__device__ __forceinline__ float bf2f(unsigned int u16) {
  return __uint_as_float(u16 << 16);
}

// round-to-nearest-even f32 -> bf16 bits
__device__ __forceinline__ unsigned short f2bf(float f) {
  unsigned int u = __float_as_uint(f);
  u += 0x7fffu + ((u >> 16) & 1u);
  return (unsigned short)(u >> 16);
}

__device__ __forceinline__ float fexp2(float x) {
#if __has_builtin(__builtin_amdgcn_exp2f)
  return __builtin_amdgcn_exp2f(x);
#else
  return exp2f(x);
#endif
}

// async global->LDS DMA, 16 B per lane; LDS dest = wave-uniform base + lane*16
__device__ __forceinline__ void gload_lds16(const void* g, void* l) {
  __builtin_amdgcn_global_load_lds(
      (const __attribute__((address_space(1))) unsigned int*)g,
      (__attribute__((address_space(3))) unsigned int*)l, 16, 0, 0);
}

// K1: fused normalize + view-sum (R9-exact). Block = batch elem b; 512 thr.
// Zeroes out[0] for K3's atomic accumulation.
__global__ __launch_bounds__(512) void k_norm_t(const float* __restrict__ feat,
                                                unsigned short* __restrict__ nrm,
                                                float* __restrict__ diag,
                                                float* __restrict__ T,
                                                float* __restrict__ out) {
  __shared__ float ldsT[VIEWS][D];
  int b = blockIdx.x;
  int t = threadIdx.x;
  if (b == 0 && t == 0) out[0] = 0.f;
  int v = t >> 5;
  int d0 = (t & 31) * 4;
  const float* src = feat + (size_t)(b * VIEWS + v) * D + d0;
  float4 x = *(const float4*)src;
  float ss = x.x * x.x + x.y * x.y + x.z * x.z + x.w * x.w;
#pragma unroll
  for (int m = 1; m < 32; m <<= 1) ss += __shfl_xor(ss, m);
  float inv = 1.0f / fmaxf(sqrtf(ss), 1e-12f);
  unsigned int u0 = f2bf(x.x * inv), u1 = f2bf(x.y * inv);
  unsigned int u2 = f2bf(x.z * inv), u3 = f2bf(x.w * inv);
  int n = v * BSZ + b;
  uint2 packed = {u0 | (u1 << 16), u2 | (u3 << 16)};
  *(uint2*)(nrm + (size_t)n * D + d0) = packed;
  float a0 = bf2f(u0), a1 = bf2f(u1), a2 = bf2f(u2), a3 = bf2f(u3);
  float ds = a0 * a0 + a1 * a1 + a2 * a2 + a3 * a3;
#pragma unroll
  for (int m = 1; m < 32; m <<= 1) ds += __shfl_xor(ds, m);
  if ((t & 31) == 0) diag[n] = ds;
  ldsT[v][d0] = a0;
  ldsT[v][d0 + 1] = a1;
  ldsT[v][d0 + 2] = a2;
  ldsT[v][d0 + 3] = a3;
  __syncthreads();
  if (t < D) {
    float acc = 0.f;
#pragma unroll
    for (int vv = 0; vv < VIEWS; ++vv) acc += ldsT[vv][t];
    T[(size_t)b * D + t] = acc;
  }
}

// K2 (fused): blocks [0,NSVC) = svcnt; blocks [NSVC, NSVC+512) = gram.
// vs R20, ONE change: wave decomposition 8x(32rows x 64cols) ->
// 8x(64rows x 32cols) [rowgrp=wid>>1, colgrp=wid&1]. B-fragments are
// wave-independent, so halving each wave's col range HALVES the block's
// total LDS B-reads (the measured dominant pipe: 2^21 conflict-cycles =
// every wave reading the whole tile). MFMA/exp totals unchanged; A-panel
// afrag[4][4] (64 VGPR); the two col-halves write disjoint epart slices
// (CSPLIT_OUT=32) -> no extra sync. Staging/DMA/swizzle/barriers R20-exact.
__global__ __launch_bounds__(512, 4) void k_gram_fused(
    const short* __restrict__ nrm, float* __restrict__ epart,
    const float* __restrict__ T, const int* __restrict__ labels,
    float* __restrict__ sv, int* __restrict__ cntc) {
  __shared__ __align__(16) char lds_raw[2][BCOLS][256];
  int tid = threadIdx.x;

  if (blockIdx.x < NSVC) {
    // ---- svcnt path: SV[c] = sum_{lbl(b)==c} T[b]; cntc[c] = count ----
    int* lab = (int*)&lds_raw[0][0][0];                 // 2 KB
    float* part = (float*)(&lds_raw[0][0][0] + 2048);   // 4x128 f32 = 2 KB
    int* pcnt = (int*)(&lds_raw[0][0][0] + 4096);       // 4 ints
    int c = blockIdx.x;
    int q = tid >> 7;        // 0..3 batch quarter
    int d = tid & 127;       // dim
    lab[tid] = labels[tid];
    __syncthreads();
    float acc = 0.f;
    int count = 0;
#pragma unroll 4
    for (int b = q * 128; b < q * 128 + 128; ++b) {
      bool m = (lab[b] == c);
      float tv = T[(size_t)b * D + d];
      acc += m ? tv : 0.f;
      count += m ? 1 : 0;
    }
    part[q * D + d] = acc;
    if (d == 0) pcnt[q] = count;
    __syncthreads();
    if (tid < D) {
      sv[c * D + tid] = part[tid] + part[D + tid] + part[2 * D + tid] + part[3 * D + tid];
      if (tid == 0) cntc[c] = pcnt[0] + pcnt[1] + pcnt[2] + pcnt[3];
    }
    return;
  }

  // ---- gram path ----
  int raw = blockIdx.x - NSVC;            // 0..511
  int bid = (raw & 7) * 64 + (raw >> 3);  // T1 XCD swizzle (bijective)
  int rowblk = bid & 31;  // 32 row-blocks of 256 rows
  int cchunk = bid >> 5;  // 0..15
  int wid = tid >> 6;
  int lane = tid & 63;
  int idx = lane & 15;
  int kg = lane >> 4;
  int rowgrp = wid >> 1;       // 0..3 -> 64-row strip
  int colgrp = wid & 1;        // 0..1 -> 32-col half of the 64-col tile
  int rowbase = rowblk * 256 + rowgrp * 64;

  // DMA staging (R20-exact): linear LDS dest, inverse-swizzled global source
  int r0 = tid >> 4;                              // 0..31
  int soff = (tid & 15) * 16;                     // 0..240
  int gsw = soff ^ ((r0 & 7) << 4);               // inverse swizzle on source
  const char* gA = (const char*)nrm + (size_t)(cchunk * (NROWS / CSPLIT) + r0) * 256 + gsw;
  // second 8KB half: rows r0+32 — same XOR since (r0+32)&7 == r0&7

  // A panel: 4 strips x 4 k-chunks, loaded once (64 VGPR)
  bf16x8 afrag[4][4];
#pragma unroll
  for (int s = 0; s < 4; ++s)
#pragma unroll
    for (int c = 0; c < 4; ++c)
      afrag[s][c] = *(const bf16x8*)(nrm + (size_t)(rowbase + s * 16 + idx) * D + c * 32 + kg * 8);

  // prologue: DMA tile 0 into buf 0
  {
    char* wb = &lds_raw[0][0][0];
    gload_lds16(gA, wb + wid * 1024);
    gload_lds16(gA + 32 * 256, wb + 8192 + wid * 1024);
  }

  f32x4 eloc[4];
#pragma unroll
  for (int s = 0; s < 4; ++s)
#pragma unroll
    for (int r = 0; r < 4; ++r) eloc[s][r] = 0.f;

  __syncthreads();

  const int NT = (NROWS / CSPLIT) / BCOLS;  // 8
  const int rdsw = (idx & 7) << 4;
  const int gbase = colgrp * 2;             // this wave's two g-groups
#pragma unroll 1
  for (int t = 0; t < NT; ++t) {
    // issue next tile's DMA early; lands before the barrier's vmcnt drain
    if (t + 1 < NT) {
      const char* gp = gA + (size_t)(t + 1) * (BCOLS * 256);
      char* wb = &lds_raw[(t + 1) & 1][0][0];
      gload_lds16(gp, wb + wid * 1024);
      gload_lds16(gp + 32 * 256, wb + 8192 + wid * 1024);
    }

    const char* buf = &lds_raw[t & 1][0][0];
#pragma unroll
    for (int gg = 0; gg < 2; ++gg) {
      int g = gbase + gg;
      bf16x8 bfrag[4];
#pragma unroll
      for (int c = 0; c < 4; ++c)
        bfrag[c] = *(const bf16x8*)(buf + (g * 16 + idx) * 256 + ((c * 64 + kg * 16) ^ rdsw));
#pragma unroll
      for (int s = 0; s < 4; ++s) {
        f32x4 acc = {0.f, 0.f, 0.f, 0.f};
#pragma unroll
        for (int c = 0; c < 4; ++c)
          acc = __builtin_amdgcn_mfma_f32_16x16x32_bf16(afrag[s][c], bfrag[c], acc, 0, 0, 0);
#pragma unroll
        for (int r = 0; r < 4; ++r)
          eloc[s][r] += fexp2(acc[r] * C1 - C1);
      }
    }

    __syncthreads();
  }

  // reduce across the 16 idx lanes (cols); write this col-half's epart slice
#pragma unroll
  for (int s = 0; s < 4; ++s)
#pragma unroll
    for (int r = 0; r < 4; ++r) {
      float vv = eloc[s][r];
      vv += __shfl_xor(vv, 1);
      vv += __shfl_xor(vv, 2);
      vv += __shfl_xor(vv, 4);
      vv += __shfl_xor(vv, 8);
      if (idx == 0)
        epart[(size_t)(cchunk * 2 + colgrp) * NROWS + rowbase + s * 16 + kg * 4 + r] = vv;
    }
}

// K3: per-row finish + fused mean. 128 blocks x 4 waves x 16 rows/wave.
// Gathers CSPLIT_OUT=32 partials (lane<32). One atomicAdd per block.
__global__ __launch_bounds__(256) void k_final(const unsigned int* __restrict__ nrm_u32,
                                               const float* __restrict__ diag,
                                               const float* __restrict__ epart,
                                               const float* __restrict__ sv,
                                               const int* __restrict__ labels,
                                               const int* __restrict__ cntc,
                                               float* __restrict__ out) {
  int w = threadIdx.x >> 6;
  int lane = threadIdx.x & 63;
  int wg = blockIdx.x * 4 + w;  // 0..511
  float lsum = 0.f;
#pragma unroll 1
  for (int i = 0; i < 16; ++i) {
    int n = wg * 16 + i;
    int b = n & (BSZ - 1);
    int lbl = labels[b];
    float2 s2 = *(const float2*)(sv + lbl * D + lane * 2);
    unsigned int u = nrm_u32[(size_t)n * (D / 2) + lane];
    float a0 = bf2f(u & 0xffffu), a1 = bf2f(u >> 16);
    float dot = a0 * s2.x + a1 * s2.y;
    float ep = (lane < CSPLIT_OUT) ? epart[(size_t)lane * NROWS + n] : 0.f;
#pragma unroll
    for (int m = 1; m < 64; m <<= 1) {
      dot += __shfl_xor(dot, m);
      ep += __shfl_xor(ep, m);
    }
    if (lane == 0) {
      float dii = diag[n];
      float Praw = dot - dii;
      float Cn = (float)(16 * cntc[lbl] - 1);
      float ediag = fexp2(dii * C1 - C1);
      float Eexcl = ep - ediag;
      float Sref = Eexcl * fexp2((1.0f - dii) * C1);
      float L = logf(Sref + 1e-12f);
      float mlpp = (Praw * INV_T - Cn * (dii * INV_T) - Cn * L) / (Cn + 1e-12f);
      lsum += -mlpp;
    }
  }
  __shared__ float part[4];
  if (lane == 0) part[w] = lsum;
  __syncthreads();
  if (threadIdx.x == 0)
    atomicAdd(out, (part[0] + part[1] + part[2] + part[3]) * (1.0f / NROWS));
}

extern "C" void kernel_launch(void* const* d_in, const int* in_sizes, int n_in,
                              void* d_out, int out_size, void* d_ws, size_t ws_size,
                              hipStream_t stream) {
  const float* feat = (const float*)d_in[0];
  const int* labels = (const int*)d_in[1];
  float* out = (float*)d_out;
  char* ws = (char*)d_ws;

  size_t off = 0;
  short* nrm = (short*)(ws + off);           off += (size_t)NROWS * D * 2;          // 2 MB
  float* diag = (float*)(ws + off);          off += (size_t)NROWS * 4;              // 32 KB
  float* epart = (float*)(ws + off);         off += (size_t)NROWS * CSPLIT_OUT * 4; // 1 MB
  float* sv = (float*)(ws + off);            off += (size_t)128 * D * 4;            // 64 KB
  int* cntc = (int*)(ws + off);              off += (size_t)128 * 4;                // 512 B
  float* T = (float*)(ws + off);             off += (size_t)BSZ * D * 4;            // 256 KB

  k_norm_t<<<BSZ, 512, 0, stream>>>(feat, (unsigned short*)nrm, diag, T, out);
  k_gram_fused<<<NSVC + 32 * CSPLIT, 512, 0, stream>>>(nrm, epart, T, labels, sv, cntc);
  k_final<<<128, 256, 0, stream>>>((const unsigned int*)nrm, diag, epart, sv, labels, cntc, out);
}

// Round 23
// 47.390 us; speedup vs baseline: 1.1510x; 1.1510x over previous
//
#include <hip/hip_runtime.h>
#include <hip/hip_bf16.h>

#define VIEWS 16
#define BSZ 512
#define NROWS 8192
#define D 128
#define CSPLIT 16
#define BCOLS 64
#define NSVC 100

typedef short bf16x8 __attribute__((ext_vector_type(8)));
typedef float f32x4 __attribute__((ext_vector_type(4)));

// log2(e)/0.07
constexpr float C1 = 20.609929155556618f;
constexpr float INV_T = 14.285714285714286f;

__device__ __forceinline__ float bf2f(unsigned int u16) {
  return __uint_as_float(u16 << 16);
}

// round-to-nearest-even f32 -> bf16 bits
__device__ __forceinline__ unsigned short f2bf(float f) {
  unsigned int u = __float_as_uint(f);
  u += 0x7fffu + ((u >> 16) & 1u);
  return (unsigned short)(u >> 16);
}

__device__ __forceinline__ float fexp2(float x) {
#if __has_builtin(__builtin_amdgcn_exp2f)
  return __builtin_amdgcn_exp2f(x);
#else
  return exp2f(x);
#endif
}

// async global->LDS DMA, 16 B per lane; LDS dest = wave-uniform base + lane*16
__device__ __forceinline__ void gload_lds16(const void* g, void* l) {
  __builtin_amdgcn_global_load_lds(
      (const __attribute__((address_space(1))) unsigned int*)g,
      (__attribute__((address_space(3))) unsigned int*)l, 16, 0, 0);
}

// K1: fused normalize + view-sum. Block = batch elem b; 512 thr.
// Zeroes out[0] for K3's atomic accumulation.
__global__ __launch_bounds__(512) void k_norm_t(const float* __restrict__ feat,
                                                unsigned short* __restrict__ nrm,
                                                float* __restrict__ diag,
                                                float* __restrict__ T,
                                                float* __restrict__ out) {
  __shared__ float ldsT[VIEWS][D];
  int b = blockIdx.x;
  int t = threadIdx.x;
  if (b == 0 && t == 0) out[0] = 0.f;
  int v = t >> 5;
  int d0 = (t & 31) * 4;
  const float* src = feat + (size_t)(b * VIEWS + v) * D + d0;
  float4 x = *(const float4*)src;
  float ss = x.x * x.x + x.y * x.y + x.z * x.z + x.w * x.w;
#pragma unroll
  for (int m = 1; m < 32; m <<= 1) ss += __shfl_xor(ss, m);
  float inv = 1.0f / fmaxf(sqrtf(ss), 1e-12f);
  unsigned int u0 = f2bf(x.x * inv), u1 = f2bf(x.y * inv);
  unsigned int u2 = f2bf(x.z * inv), u3 = f2bf(x.w * inv);
  int n = v * BSZ + b;
  uint2 packed = {u0 | (u1 << 16), u2 | (u3 << 16)};
  *(uint2*)(nrm + (size_t)n * D + d0) = packed;
  float a0 = bf2f(u0), a1 = bf2f(u1), a2 = bf2f(u2), a3 = bf2f(u3);
  float ds = a0 * a0 + a1 * a1 + a2 * a2 + a3 * a3;
#pragma unroll
  for (int m = 1; m < 32; m <<= 1) ds += __shfl_xor(ds, m);
  if ((t & 31) == 0) diag[n] = ds;
  ldsT[v][d0] = a0;
  ldsT[v][d0 + 1] = a1;
  ldsT[v][d0 + 2] = a2;
  ldsT[v][d0 + 3] = a3;
  __syncthreads();
  if (t < D) {
    float acc = 0.f;
#pragma unroll
    for (int vv = 0; vv < VIEWS; ++vv) acc += ldsT[vv][t];
    T[(size_t)b * D + t] = acc;
  }
}

// K2 (fused): blocks [0,NSVC) = svcnt; blocks [NSVC, NSVC+512) = gram.
// Best-measured gram (R20): 8 waves, 32 rows/wave, BCOLS=64, NT=8,
// global_load_lds DMA staging (linear LDS dest, inverse-swizzled global
// source per rule #21), XOR-swizzled ds reads, double-buffered 2x16KB.
__global__ __launch_bounds__(512, 4) void k_gram_fused(
    const short* __restrict__ nrm, float* __restrict__ epart,
    const float* __restrict__ T, const int* __restrict__ labels,
    float* __restrict__ sv, int* __restrict__ cntc) {
  __shared__ __align__(16) char lds_raw[2][BCOLS][256];
  int tid = threadIdx.x;

  if (blockIdx.x < NSVC) {
    // ---- svcnt path: SV[c] = sum_{lbl(b)==c} T[b]; cntc[c] = count ----
    int* lab = (int*)&lds_raw[0][0][0];                 // 2 KB
    float* part = (float*)(&lds_raw[0][0][0] + 2048);   // 4x128 f32 = 2 KB
    int* pcnt = (int*)(&lds_raw[0][0][0] + 4096);       // 4 ints
    int c = blockIdx.x;
    int q = tid >> 7;        // 0..3 batch quarter
    int d = tid & 127;       // dim
    lab[tid] = labels[tid];
    __syncthreads();
    float acc = 0.f;
    int count = 0;
#pragma unroll 4
    for (int b = q * 128; b < q * 128 + 128; ++b) {
      bool m = (lab[b] == c);
      float tv = T[(size_t)b * D + d];
      acc += m ? tv : 0.f;
      count += m ? 1 : 0;
    }
    part[q * D + d] = acc;
    if (d == 0) pcnt[q] = count;
    __syncthreads();
    if (tid < D) {
      sv[c * D + tid] = part[tid] + part[D + tid] + part[2 * D + tid] + part[3 * D + tid];
      if (tid == 0) cntc[c] = pcnt[0] + pcnt[1] + pcnt[2] + pcnt[3];
    }
    return;
  }

  // ---- gram path ----
  int bid = blockIdx.x - NSVC;
  int rowblk = bid & 31;  // 32 row-blocks of 256 rows
  int cchunk = bid >> 5;  // 0..15
  int wid = tid >> 6;
  int lane = tid & 63;
  int idx = lane & 15;
  int kg = lane >> 4;
  int rowbase = rowblk * 256 + wid * 32;

  // DMA staging: thread's linear LDS slot = tid*16 (row r0 = tid>>4,
  // col soff = (tid&15)*16); global source pre-swizzled by the read XOR.
  int r0 = tid >> 4;                              // 0..31
  int soff = (tid & 15) * 16;                     // 0..240
  int gsw = soff ^ ((r0 & 7) << 4);               // inverse swizzle on source
  const char* gA = (const char*)nrm + (size_t)(cchunk * (NROWS / CSPLIT) + r0) * 256 + gsw;
  // second 8KB half: rows r0+32 — same XOR since (r0+32)&7 == r0&7

  // A panel: 2 strips x 4 k-chunks, loaded once
  bf16x8 afrag[2][4];
#pragma unroll
  for (int s = 0; s < 2; ++s)
#pragma unroll
    for (int c = 0; c < 4; ++c)
      afrag[s][c] = *(const bf16x8*)(nrm + (size_t)(rowbase + s * 16 + idx) * D + c * 32 + kg * 8);

  // prologue: DMA tile 0 into buf 0
  {
    char* wb = &lds_raw[0][0][0];
    gload_lds16(gA, wb + wid * 1024);
    gload_lds16(gA + 32 * 256, wb + 8192 + wid * 1024);
  }

  f32x4 eloc[2][4];
#pragma unroll
  for (int s = 0; s < 2; ++s)
#pragma unroll
    for (int g = 0; g < 4; ++g)
#pragma unroll
      for (int r = 0; r < 4; ++r) eloc[s][g][r] = 0.f;

  __syncthreads();

  const int NT = (NROWS / CSPLIT) / BCOLS;  // 8
  const int rdsw = (idx & 7) << 4;
#pragma unroll 1
  for (int t = 0; t < NT; ++t) {
    // issue next tile's DMA early; lands before the barrier's vmcnt drain
    if (t + 1 < NT) {
      const char* gp = gA + (size_t)(t + 1) * (BCOLS * 256);
      char* wb = &lds_raw[(t + 1) & 1][0][0];
      gload_lds16(gp, wb + wid * 1024);
      gload_lds16(gp + 32 * 256, wb + 8192 + wid * 1024);
    }

    const char* buf = &lds_raw[t & 1][0][0];
#pragma unroll
    for (int g = 0; g < 4; ++g) {
      bf16x8 bfrag[4];
#pragma unroll
      for (int c = 0; c < 4; ++c)
        bfrag[c] = *(const bf16x8*)(buf + (g * 16 + idx) * 256 + ((c * 64 + kg * 16) ^ rdsw));
#pragma unroll
      for (int s = 0; s < 2; ++s) {
        f32x4 acc = {0.f, 0.f, 0.f, 0.f};
#pragma unroll
        for (int c = 0; c < 4; ++c)
          acc = __builtin_amdgcn_mfma_f32_16x16x32_bf16(afrag[s][c], bfrag[c], acc, 0, 0, 0);
#pragma unroll
        for (int r = 0; r < 4; ++r)
          eloc[s][g][r] += fexp2(acc[r] * C1 - C1);
      }
    }

    __syncthreads();
  }

  // sum the four col-groups, reduce across the 16 idx lanes, write partials
#pragma unroll
  for (int s = 0; s < 2; ++s)
#pragma unroll
    for (int r = 0; r < 4; ++r) {
      float vv = eloc[s][0][r] + eloc[s][1][r] + eloc[s][2][r] + eloc[s][3][r];
      vv += __shfl_xor(vv, 1);
      vv += __shfl_xor(vv, 2);
      vv += __shfl_xor(vv, 4);
      vv += __shfl_xor(vv, 8);
      if (idx == 0)
        epart[(size_t)cchunk * NROWS + rowbase + s * 16 + kg * 4 + r] = vv;
    }
}

// K3: per-row finish + fused mean. 128 blocks x 4 waves x 16 rows/wave.
// One atomicAdd per block (128 total; out zeroed by k_norm_t).
__global__ __launch_bounds__(256) void k_final(const unsigned int* __restrict__ nrm_u32,
                                               const float* __restrict__ diag,
                                               const float* __restrict__ epart,
                                               const float* __restrict__ sv,
                                               const int* __restrict__ labels,
                                               const int* __restrict__ cntc,
                                               float* __restrict__ out) {
  int w = threadIdx.x >> 6;
  int lane = threadIdx.x & 63;
  int wg = blockIdx.x * 4 + w;  // 0..511
  float lsum = 0.f;
#pragma unroll 1
  for (int i = 0; i < 16; ++i) {
    int n = wg * 16 + i;
    int b = n & (BSZ - 1);
    int lbl = labels[b];
    float2 s2 = *(const float2*)(sv + lbl * D + lane * 2);
    unsigned int u = nrm_u32[(size_t)n * (D / 2) + lane];
    float a0 = bf2f(u & 0xffffu), a1 = bf2f(u >> 16);
    float dot = a0 * s2.x + a1 * s2.y;
    float ep = (lane < CSPLIT) ? epart[(size_t)lane * NROWS + n] : 0.f;
#pragma unroll
    for (int m = 1; m < 64; m <<= 1) {
      dot += __shfl_xor(dot, m);
      ep += __shfl_xor(ep, m);
    }
    if (lane == 0) {
      float dii = diag[n];
      float Praw = dot - dii;
      float Cn = (float)(16 * cntc[lbl] - 1);
      float ediag = fexp2(dii * C1 - C1);
      float Eexcl = ep - ediag;
      float Sref = Eexcl * fexp2((1.0f - dii) * C1);
      float L = logf(Sref + 1e-12f);
      float mlpp = (Praw * INV_T - Cn * (dii * INV_T) - Cn * L) / (Cn + 1e-12f);
      lsum += -mlpp;
    }
  }
  __shared__ float part[4];
  if (lane == 0) part[w] = lsum;
  __syncthreads();
  if (threadIdx.x == 0)
    atomicAdd(out, (part[0] + part[1] + part[2] + part[3]) * (1.0f / NROWS));
}

extern "C" void kernel_launch(void* const* d_in, const int* in_sizes, int n_in,
                              void* d_out, int out_size, void* d_ws, size_t ws_size,
                              hipStream_t stream) {
  const float* feat = (const float*)d_in[0];
  const int* labels = (const int*)d_in[1];
  float* out = (float*)d_out;
  char* ws = (char*)d_ws;

  size_t off = 0;
  short* nrm = (short*)(ws + off);           off += (size_t)NROWS * D * 2;        // 2 MB
  float* diag = (float*)(ws + off);          off += (size_t)NROWS * 4;            // 32 KB
  float* epart = (float*)(ws + off);         off += (size_t)NROWS * CSPLIT * 4;   // 512 KB
  float* sv = (float*)(ws + off);            off += (size_t)128 * D * 4;          // 64 KB
  int* cntc = (int*)(ws + off);              off += (size_t)128 * 4;              // 512 B
  float* T = (float*)(ws + off);             off += (size_t)BSZ * D * 4;          // 256 KB

  k_norm_t<<<BSZ, 512, 0, stream>>>(feat, (unsigned short*)nrm, diag, T, out);
  k_gram_fused<<<NSVC + 32 * CSPLIT, 512, 0, stream>>>(nrm, epart, T, labels, sv, cntc);
  k_final<<<128, 256, 0, stream>>>((const unsigned int*)nrm, diag, epart, sv, labels, cntc, out);
}